// Round 2
// baseline (604.449 us; speedup 1.0000x reference)
//
#include <hip/hip_runtime.h>
#include <hip/hip_cooperative_groups.h>
#include <math.h>

namespace cg = cooperative_groups;

// DigitCaps dynamic routing. B=256, R=1152, C=10, O=16, I=8, 3 iters.
// R15: single persistent cooperative kernel, STATIC 120.8KB LDS (dynamic-LDS
// opt-in suspected as R14's silent launch failure). X(bf16) + W(fp32) staged
// to LDS once; grid.sync() replaces 7 kernel boundaries; gtdot V-fragments
// read direct from global vt (L2). Fallback to verified R13 3-kernel path if
// hipLaunchCooperativeKernel returns an error (no more silent zeros).

#define B_ 256
#define R_ 1152
#define N_ 160      // C*O
#define K_ 9216     // R*I
#define NS 128      // K splits of 72 (9 routes)
#define KB 72
#define LDK 104     // gemm LDS k-stride (bf16 elems)
#define LDB 136     // gtdot LDS b-stride (bf16 elems)

// workspace layout (byte offsets)
#define PART_ELEMS ((size_t)B_*NS*N_)          // 5,242,880 fp16 = 10.49 MB
#define BIJ_BOFF   (PART_ELEMS*2)
#define VT_BOFF    (BIJ_BOFF + (size_t)R_*10*4)

// static LDS pool (byte offsets)
#define ASG_OFF    0            // short[128*LDK]   26,624 B (persistent)
#define WF_OFF     26624        // float[160*72]    46,080 B (persistent)
#define SCR_OFF    72704        // scratch          47,520 B
//   gemm : Bs  short[160*LDK] 33,280 B
//   gtdot: Ast short[80*LDB]  21,760 B ; then LG float[72*165] 47,520 B
#define SMEM_BYTES 120224

typedef __attribute__((ext_vector_type(8))) short short8;
typedef __attribute__((ext_vector_type(4))) float f32x4;

static __device__ __forceinline__ short f2bf(float f) {   // RNE fp32->bf16
    unsigned u = __float_as_uint(f);
    unsigned r = (u + 0x7fffu + ((u >> 16) & 1u)) >> 16;
    return (short)r;
}

// ===========================================================================
// Fused cooperative kernel
// ===========================================================================
__global__ __launch_bounds__(256) void k_caps(const float* __restrict__ X,
                                              const float* __restrict__ W,
                                              _Float16* __restrict__ part,
                                              float* __restrict__ bij,
                                              short* __restrict__ vt,
                                              float* __restrict__ out) {
    cg::grid_group grid = cg::this_grid();
    __shared__ __align__(16) char smem[SMEM_BYTES];
    short* Asg = (short*)(smem + ASG_OFF);   // [b][k] bf16, persistent
    float* Wf  = (float*)(smem + WF_OFF);    // [n=c*16+o][k=rl*8+i] fp32, persistent
    short* Bs  = (short*)(smem + SCR_OFF);   // gemm: scaled W [n][k] bf16
    short* Ast = (short*)(smem + SCR_OFF);   // gtdot: X^T [k][b] bf16
    float* LG  = (float*)(smem + SCR_OFF);   // gtdot: G [72][165] fp32
    __shared__ float cs[90];
    __shared__ float red[40];
    __shared__ float dsm[10];

    const int tid = threadIdx.x;
    const int ks = blockIdx.x >> 1, bt = blockIdx.x & 1;  // == (kt, bh)
    const int b0 = bt * 128, k0 = ks * KB, r0 = ks * 9;

    // ---------------- P0: one-time persistent staging ----------------
    // X[128][72] -> bf16 Asg[b][k]
    #pragma unroll
    for (int j = 0; j < 9; ++j) {
        int q = j * 256 + tid;                     // < 2304
        int bb = q / 18, kf = q - bb * 18;
        float4 a = *(const float4*)(X + (size_t)(b0 + bb) * K_ + k0 + kf * 4);
        short4 h = make_short4(f2bf(a.x), f2bf(a.y), f2bf(a.z), f2bf(a.w));
        *(short4*)(&Asg[bb * LDK + kf * 4]) = h;
    }
    // zero Asg k-pad [72,96)
    #pragma unroll
    for (int j = 0; j < 3; ++j) {
        int q = j * 256 + tid;                     // < 768 = 128*6
        int bb = q / 6, ch = q - bb * 6;
        *(short4*)(&Asg[bb * LDK + 72 + ch * 4]) = make_short4(0, 0, 0, 0);
    }
    // W slice (9 routes) -> fp32 Wf[n][k]
    {
        const float* Wsl = W + (size_t)r0 * 1280;
        #pragma unroll
        for (int j = 0; j < 12; ++j) {
            int q = j * 256 + tid;
            if (q < 2880) {
                int rl = q / 320;
                int rem = q - rl * 320;
                int c = rem >> 5;
                int o = (rem & 31) >> 1;
                int i4 = rem & 1;
                float4 w = *(const float4*)(Wsl + (size_t)q * 4);
                *(float4*)(&Wf[(c * 16 + o) * 72 + rl * 8 + i4 * 4]) = w;
            }
        }
    }
    if (bt == 0 && tid < 90) bij[r0 * 10 + tid] = 0.0f;

    for (int it = 0; it < 3; ++it) {
        // ---------------- coupling coefficients cs[9][10] ----------------
        if (it == 0) {
            if (tid < 90) cs[tid] = 1.0f / 1152.0f;
        } else {
            float dcol[10];
            #pragma unroll
            for (int c = 0; c < 10; ++c) dcol[c] = 0.0f;
            for (int r = tid; r < R_; r += 256) {
                #pragma unroll
                for (int c = 0; c < 10; ++c) dcol[c] += __expf(bij[r * 10 + c]);
            }
            const int lane = tid & 63, wv = tid >> 6;
            #pragma unroll
            for (int c = 0; c < 10; ++c) {
                float s = dcol[c];
                #pragma unroll
                for (int off = 32; off > 0; off >>= 1) s += __shfl_down(s, off);
                if (lane == 0) red[wv * 10 + c] = s;
            }
            __syncthreads();
            if (tid < 10)
                dsm[tid] = red[tid] + red[10 + tid] + red[20 + tid] + red[30 + tid];
            __syncthreads();
            if (tid < 90) {
                int rr = tid / 10, cc = tid - rr * 10;
                cs[tid] = __expf(bij[(r0 + rr) * 10 + cc]) / dsm[cc];
            }
        }
        __syncthreads();   // cs ready (also orders P0 staging on iter 0)

        // ---------------- Bs = (cs ⊙ W) bf16, from LDS fp32 Wf ----------------
        #pragma unroll
        for (int j = 0; j < 12; ++j) {
            int q = j * 256 + tid;
            if (q < 2880) {                         // 160 rows * 18 float4
                int nn = q / 18, kk4 = q - nn * 18;
                float4 w = *(const float4*)(Wf + nn * 72 + kk4 * 4);
                int rl = kk4 >> 1;
                float sc = cs[rl * 10 + (nn >> 4)];
                short4 h = make_short4(f2bf(w.x * sc), f2bf(w.y * sc),
                                       f2bf(w.z * sc), f2bf(w.w * sc));
                *(short4*)(&Bs[nn * LDK + kk4 * 4]) = h;
            }
        }
        #pragma unroll
        for (int j = 0; j < 4; ++j) {
            int q = j * 256 + tid;
            if (q < 960) {                          // 160 rows * 6 pad chunks
                int nn = q / 6, ch = q - nn * 6;
                *(short4*)(&Bs[nn * LDK + 72 + ch * 4]) = make_short4(0, 0, 0, 0);
            }
        }
        __syncthreads();

        // ---------------- GEMM: part[b][ks][n] ----------------
        {
            const int wv = tid >> 6, lane = tid & 63;
            const int lrow = lane & 15, quad = lane >> 4;
            f32x4 acc[2][10];
            #pragma unroll
            for (int mi = 0; mi < 2; ++mi)
                #pragma unroll
                for (int nt = 0; nt < 10; ++nt) acc[mi][nt] = (f32x4)(0.0f);

            #pragma unroll
            for (int ksp = 0; ksp < 3; ++ksp) {
                const int ko = ksp * 32 + quad * 8;
                short8 afr[2], bfr[10];
                #pragma unroll
                for (int mi = 0; mi < 2; ++mi)
                    afr[mi] = *(const short8*)(&Asg[((wv * 2 + mi) * 16 + lrow) * LDK + ko]);
                #pragma unroll
                for (int nt = 0; nt < 10; ++nt)
                    bfr[nt] = *(const short8*)(&Bs[(nt * 16 + lrow) * LDK + ko]);
                #pragma unroll
                for (int mi = 0; mi < 2; ++mi)
                    #pragma unroll
                    for (int nt = 0; nt < 10; ++nt)
                        acc[mi][nt] = __builtin_amdgcn_mfma_f32_16x16x32_bf16(
                            afr[mi], bfr[nt], acc[mi][nt], 0, 0, 0);
            }
            // C store (fp16): row=(quad*4+reg), col=lrow
            #pragma unroll
            for (int mi = 0; mi < 2; ++mi) {
                int bbase = b0 + (wv * 2 + mi) * 16 + quad * 4;
                #pragma unroll
                for (int reg = 0; reg < 4; ++reg) {
                    _Float16* P = part + (size_t)(bbase + reg) * (NS * N_) + ks * N_ + lrow;
                    #pragma unroll
                    for (int nt = 0; nt < 10; ++nt)
                        P[nt * 16] = (_Float16)acc[mi][nt][reg];
                }
            }
        }
        __threadfence();
        grid.sync();

        // ---------------- reduce + squash (b = blockIdx.x) ----------------
        if (tid < 160) {
            const int b = blockIdx.x;
            const _Float16* p = part + (size_t)b * (NS * N_) + tid;
            float s = 0.0f;
            #pragma unroll 8
            for (int kk = 0; kk < NS; ++kk) s += (float)p[kk * N_];
            float v = s * fabsf(s) / (1.0f + s * s);   // elementwise squash
            if (it == 2) out[b * N_ + tid] = v;
            else         vt[tid * 256 + b] = f2bf(v);
        }
        if (it == 2) break;
        __threadfence();
        grid.sync();

        // ---------- gtdot: G = X^T.V-half, then bij += W·G/B ----------
        // Ast[k][b] from persistent Asg[b][k] (LDS->LDS transpose)
        #pragma unroll
        for (int j = 0; j < 9; ++j) {
            int q = j * 256 + tid;                 // < 2304 = 128*18
            int bb = q / 18, kf = q - bb * 18;
            short4 a = *(const short4*)(&Asg[bb * LDK + kf * 4]);
            Ast[(kf * 4 + 0) * LDB + bb] = a.x;
            Ast[(kf * 4 + 1) * LDB + bb] = a.y;
            Ast[(kf * 4 + 2) * LDB + bb] = a.z;
            Ast[(kf * 4 + 3) * LDB + bb] = a.w;
        }
        __syncthreads();

        {
            const int wv = tid >> 6, lane = tid & 63;
            const int lrow = lane & 15, quad = lane >> 4;
            f32x4 acc[5][3];
            #pragma unroll
            for (int mt = 0; mt < 5; ++mt)
                #pragma unroll
                for (int sl = 0; sl < 3; ++sl) acc[mt][sl] = (f32x4)(0.0f);

            #pragma unroll
            for (int kb = 0; kb < 4; ++kb) {
                const int ko = kb * 32 + quad * 8;
                short8 af[5], bf[3];
                #pragma unroll
                for (int mt = 0; mt < 5; ++mt)
                    af[mt] = *(const short8*)(&Ast[(mt * 16 + lrow) * LDB + ko]);
                // V fragments direct from global vt[n][256b] (L2-resident)
                #pragma unroll
                for (int sl = 0; sl < 3; ++sl) {
                    int nt = wv + sl * 4;
                    if (nt < 10)
                        bf[sl] = *(const short8*)(vt + (nt * 16 + lrow) * 256 + b0 + ko);
                }
                #pragma unroll
                for (int mt = 0; mt < 5; ++mt)
                    #pragma unroll
                    for (int sl = 0; sl < 3; ++sl)
                        if (wv + sl * 4 < 10)
                            acc[mt][sl] = __builtin_amdgcn_mfma_f32_16x16x32_bf16(
                                af[mt], bf[sl], acc[mt][sl], 0, 0, 0);
            }
            __syncthreads();   // frag reads done; reuse scratch as LG

            #pragma unroll
            for (int mt = 0; mt < 5; ++mt) {
                #pragma unroll
                for (int sl = 0; sl < 3; ++sl) {
                    int nt = wv + sl * 4;
                    if (nt < 10) {
                        #pragma unroll
                        for (int reg = 0; reg < 4; ++reg) {
                            int m = mt * 16 + quad * 4 + reg;
                            if (m < 72)
                                LG[m * 165 + nt * 16 + lrow] = acc[mt][sl][reg];
                        }
                    }
                }
            }
        }
        __syncthreads();
        // per-route dot with W (fp32 from LDS), atomicAdd into bij
        if (tid < 90) {
            int rl = tid / 10, c = tid - rl * 10;
            int r = r0 + rl;
            const float* wbase = Wf + (c * 16) * 72 + rl * 8;
            float s = 0.0f;
            #pragma unroll
            for (int o = 0; o < 16; ++o) {
                const float* wp = wbase + o * 72;
                float4 wa = *(const float4*)(wp);
                float4 wb = *(const float4*)(wp + 4);
                const float* g = &LG[(rl * 8) * 165 + c * 16 + o];
                s += wa.x * g[0]       + wa.y * g[165]     + wa.z * g[2 * 165] +
                     wa.w * g[3 * 165] + wb.x * g[4 * 165] + wb.y * g[5 * 165] +
                     wb.z * g[6 * 165] + wb.w * g[7 * 165];
            }
            atomicAdd(&bij[r * 10 + c], s * (1.0f / B_));
        }
        __threadfence();
        grid.sync();
    }
}

// ===========================================================================
// Fallback path: verified R13 kernels (131.9 us) — used only if the
// cooperative launch is rejected. Guarantees no silent-zero failure.
// ===========================================================================
__global__ __launch_bounds__(256) void k_gemm(const float* __restrict__ X,
                                              const float* __restrict__ W,
                                              float* __restrict__ bij,
                                              _Float16* __restrict__ part,
                                              int it) {
    __shared__ short As[128 * LDK];
    __shared__ short BsF[160 * LDK];
    __shared__ float cs[90];
    __shared__ float red[40];
    __shared__ float dsm[10];
    const int tid = threadIdx.x;
    const int ks = blockIdx.x >> 1, bt = blockIdx.x & 1;
    const int b0 = bt * 128, k0 = ks * KB, r0 = ks * 9;

    if (it == 0) {
        if (tid < 90) cs[tid] = 1.0f / 1152.0f;
        if (bt == 0 && tid < 90) bij[r0 * 10 + tid] = 0.0f;
    } else {
        float dcol[10];
        #pragma unroll
        for (int c = 0; c < 10; ++c) dcol[c] = 0.0f;
        for (int r = tid; r < R_; r += 256) {
            #pragma unroll
            for (int c = 0; c < 10; ++c) dcol[c] += __expf(bij[r * 10 + c]);
        }
        const int lane = tid & 63, wv = tid >> 6;
        #pragma unroll
        for (int c = 0; c < 10; ++c) {
            float s = dcol[c];
            #pragma unroll
            for (int off = 32; off > 0; off >>= 1) s += __shfl_down(s, off);
            if (lane == 0) red[wv * 10 + c] = s;
        }
        __syncthreads();
        if (tid < 10)
            dsm[tid] = red[tid] + red[10 + tid] + red[20 + tid] + red[30 + tid];
        __syncthreads();
        if (tid < 90) {
            int rr = tid / 10, cc = tid - rr * 10;
            cs[tid] = __expf(bij[(r0 + rr) * 10 + cc]) / dsm[cc];
        }
    }

    #pragma unroll
    for (int j = 0; j < 9; ++j) {
        int q = j * 256 + tid;
        int bb = q / 18, kf = q - bb * 18;
        float4 a = *(const float4*)(X + (size_t)(b0 + bb) * K_ + k0 + kf * 4);
        short4 h = make_short4(f2bf(a.x), f2bf(a.y), f2bf(a.z), f2bf(a.w));
        *(short4*)(&As[bb * LDK + kf * 4]) = h;
    }
    #pragma unroll
    for (int j = 0; j < 3; ++j) {
        int q = j * 256 + tid;
        int bb = q / 6, ch = q - bb * 6;
        *(short4*)(&As[bb * LDK + 72 + ch * 4]) = make_short4(0, 0, 0, 0);
    }
    {
        const float* Wsl = W + (size_t)r0 * 1280;
        #pragma unroll
        for (int j = 0; j < 12; ++j) {
            int q = j * 256 + tid;
            if (q < 2880) {
                int rl = q / 320;
                int rem = q - rl * 320;
                int c = rem >> 5;
                int o = (rem & 31) >> 1;
                int i4 = rem & 1;
                float4 w = *(const float4*)(Wsl + (size_t)q * 4);
                float sc = cs[rl * 10 + c];
                int nn = c * 16 + o;
                int kk = rl * 8 + i4 * 4;
                short4 h = make_short4(f2bf(w.x * sc), f2bf(w.y * sc),
                                       f2bf(w.z * sc), f2bf(w.w * sc));
                *(short4*)(&BsF[nn * LDK + kk]) = h;
            }
        }
        #pragma unroll
        for (int j = 0; j < 4; ++j) {
            int q = j * 256 + tid;
            if (q < 960) {
                int nn = q / 6, ch = q - nn * 6;
                *(short4*)(&BsF[nn * LDK + 72 + ch * 4]) = make_short4(0, 0, 0, 0);
            }
        }
    }
    __syncthreads();

    const int wv = tid >> 6, lane = tid & 63;
    const int lrow = lane & 15, quad = lane >> 4;
    f32x4 acc[2][10];
    #pragma unroll
    for (int mi = 0; mi < 2; ++mi)
        #pragma unroll
        for (int nt = 0; nt < 10; ++nt) acc[mi][nt] = (f32x4)(0.0f);

    #pragma unroll
    for (int ksp = 0; ksp < 3; ++ksp) {
        const int ko = ksp * 32 + quad * 8;
        short8 afr[2], bfr[10];
        #pragma unroll
        for (int mi = 0; mi < 2; ++mi)
            afr[mi] = *(const short8*)(&As[((wv * 2 + mi) * 16 + lrow) * LDK + ko]);
        #pragma unroll
        for (int nt = 0; nt < 10; ++nt)
            bfr[nt] = *(const short8*)(&BsF[(nt * 16 + lrow) * LDK + ko]);
        #pragma unroll
        for (int mi = 0; mi < 2; ++mi)
            #pragma unroll
            for (int nt = 0; nt < 10; ++nt)
                acc[mi][nt] = __builtin_amdgcn_mfma_f32_16x16x32_bf16(
                    afr[mi], bfr[nt], acc[mi][nt], 0, 0, 0);
    }

    #pragma unroll
    for (int mi = 0; mi < 2; ++mi) {
        int bbase = b0 + (wv * 2 + mi) * 16 + quad * 4;
        #pragma unroll
        for (int reg = 0; reg < 4; ++reg) {
            _Float16* P = part + (size_t)(bbase + reg) * (NS * N_) + ks * N_ + lrow;
            #pragma unroll
            for (int nt = 0; nt < 10; ++nt)
                P[nt * 16] = (_Float16)acc[mi][nt][reg];
        }
    }
}

__global__ void k_reduce(const _Float16* __restrict__ part,
                         float* __restrict__ out,
                         short* __restrict__ vt, int fin) {
    const int n = threadIdx.x, b = blockIdx.x;
    if (n < 160) {
        const _Float16* p = part + (size_t)b * (NS * N_) + n;
        float s = 0.0f;
        #pragma unroll 8
        for (int ks = 0; ks < NS; ++ks) s += (float)p[ks * N_];
        float v = s * fabsf(s) / (1.0f + s * s);
        if (fin) out[b * N_ + n] = v;
        else     vt[n * 256 + b] = f2bf(v);
    }
}

__global__ __launch_bounds__(256) void k_gtdot(const float* __restrict__ X,
                                               const float* __restrict__ W,
                                               const short* __restrict__ Vt,
                                               float* __restrict__ bij) {
    __shared__ short SM2[32640];
    short* As = SM2;
    short* Bs2 = SM2 + 80 * LDB;
    float* LG = (float*)SM2;
    const int tid = threadIdx.x;
    const int kt = blockIdx.x >> 1, bh = blockIdx.x & 1;
    const int k0 = kt * 72, r0 = kt * 9, b0 = bh * 128;

    #pragma unroll
    for (int j = 0; j < 9; ++j) {
        int q = j * 256 + tid;
        int bb = q / 18, kf = q - bb * 18;
        float4 a = *(const float4*)(X + (size_t)(b0 + bb) * K_ + k0 + kf * 4);
        As[(kf * 4 + 0) * LDB + bb] = f2bf(a.x);
        As[(kf * 4 + 1) * LDB + bb] = f2bf(a.y);
        As[(kf * 4 + 2) * LDB + bb] = f2bf(a.z);
        As[(kf * 4 + 3) * LDB + bb] = f2bf(a.w);
    }
    #pragma unroll
    for (int j = 0; j < 10; ++j) {
        int q = j * 256 + tid;
        int n = q >> 4, s = q & 15;
        *(short8*)(&Bs2[n * LDB + s * 8]) =
            *(const short8*)(Vt + n * 256 + b0 + s * 8);
    }
    __syncthreads();

    const int wv = tid >> 6, lane = tid & 63;
    const int lrow = lane & 15, quad = lane >> 4;
    f32x4 acc[5][3];
    #pragma unroll
    for (int mt = 0; mt < 5; ++mt)
        #pragma unroll
        for (int sl = 0; sl < 3; ++sl) acc[mt][sl] = (f32x4)(0.0f);

    #pragma unroll
    for (int kb = 0; kb < 4; ++kb) {
        const int ko = kb * 32 + quad * 8;
        short8 af[5], bf[3];
        #pragma unroll
        for (int mt = 0; mt < 5; ++mt)
            af[mt] = *(const short8*)(&As[(mt * 16 + lrow) * LDB + ko]);
        #pragma unroll
        for (int sl = 0; sl < 3; ++sl) {
            int nt = wv + sl * 4;
            if (nt < 10)
                bf[sl] = *(const short8*)(&Bs2[(nt * 16 + lrow) * LDB + ko]);
        }
        #pragma unroll
        for (int mt = 0; mt < 5; ++mt)
            #pragma unroll
            for (int sl = 0; sl < 3; ++sl)
                if (wv + sl * 4 < 10)
                    acc[mt][sl] = __builtin_amdgcn_mfma_f32_16x16x32_bf16(
                        af[mt], bf[sl], acc[mt][sl], 0, 0, 0);
    }
    __syncthreads();

    #pragma unroll
    for (int mt = 0; mt < 5; ++mt) {
        #pragma unroll
        for (int sl = 0; sl < 3; ++sl) {
            int nt = wv + sl * 4;
            if (nt < 10) {
                #pragma unroll
                for (int reg = 0; reg < 4; ++reg) {
                    int m = mt * 16 + quad * 4 + reg;
                    if (m < 72)
                        LG[m * 165 + nt * 16 + lrow] = acc[mt][sl][reg];
                }
            }
        }
    }
    __syncthreads();
    if (tid < 90) {
        int rl = tid / 10, c = tid - rl * 10;
        int r = r0 + rl;
        const float4* wp = (const float4*)(W + (size_t)r * 1280 + c * 128);
        float s = 0.0f;
        #pragma unroll
        for (int o = 0; o < 16; ++o) {
            float4 wa = wp[o * 2], wb = wp[o * 2 + 1];
            const float* g = &LG[(rl * 8) * 165 + c * 16 + o];
            s += wa.x * g[0]       + wa.y * g[165]     + wa.z * g[2 * 165] +
                 wa.w * g[3 * 165] + wb.x * g[4 * 165] + wb.y * g[5 * 165] +
                 wb.z * g[6 * 165] + wb.w * g[7 * 165];
        }
        atomicAdd(&bij[r * 10 + c], s * (1.0f / B_));
    }
}

// ---------------------------------------------------------------------------
extern "C" void kernel_launch(void* const* d_in, const int* in_sizes, int n_in,
                              void* d_out, int out_size, void* d_ws, size_t ws_size,
                              hipStream_t stream) {
    const float* x = (const float*)d_in[0];   // (256, 1152, 8)
    const float* W = (const float*)d_in[1];   // (1152, 10, 16, 8)
    char* ws       = (char*)d_ws;
    _Float16* part = (_Float16*)ws;
    float* bij     = (float*)(ws + BIJ_BOFF);
    short* vt      = (short*)(ws + VT_BOFF);  // Vt[160][256] bf16
    float* outf    = (float*)d_out;

    void* args[] = {(void*)&x, (void*)&W, (void*)&part,
                    (void*)&bij, (void*)&vt, (void*)&outf};
    hipError_t e = hipLaunchCooperativeKernel((const void*)k_caps, dim3(256),
                                              dim3(256), args, 0, stream);
    if (e != hipSuccess) {
        // fallback: verified 8-dispatch path
        for (int it = 0; it < 3; ++it) {
            k_gemm<<<256, 256, 0, stream>>>(x, W, bij, part, it);
            k_reduce<<<256, 256, 0, stream>>>(part, outf, vt, it == 2);
            if (it < 2) k_gtdot<<<256, 256, 0, stream>>>(x, W, vt, bij);
        }
    }
}

// Round 3
// 386.777 us; speedup vs baseline: 1.5628x; 1.5628x over previous
//
#include <hip/hip_runtime.h>
#include <math.h>

// DigitCaps dynamic routing. B=256, R=1152, C=10, O=16, I=8, 3 iters.
// R16: cooperative persistent kernel with CUSTOM grid barrier. R15 showed
// cg::grid_group::sync() costs ~70us each (7 syncs = ~490us of the 550us
// kernel; MfmaUtil 0.33%). Replace with memset-initialized counting
// barriers: hipMemsetAsync zeroes 7 counters per launch (captured in the
// graph), arrive = atomic_fetch_add(RELEASE, AGENT) (does the required L2
// writeback for cross-XCD visibility of part/vt/bij), spin = RELAXED agent
// loads + s_sleep backoff, pass = ACQUIRE agent fence. Dataflow/numerics
// identical to R15 (passed, absmax 4.9e-4). Fallback: verified R13 path.

#define B_ 256
#define R_ 1152
#define N_ 160      // C*O
#define K_ 9216     // R*I
#define NS 128      // K splits of 72 (9 routes)
#define KB 72
#define LDK 104     // gemm LDS k-stride (bf16 elems)
#define LDB 136     // gtdot LDS b-stride (bf16 elems)

// workspace layout (byte offsets)
#define PART_ELEMS ((size_t)B_*NS*N_)          // 5,242,880 fp16 = 10.49 MB
#define BIJ_BOFF   (PART_ELEMS*2)
#define VT_BOFF    (BIJ_BOFF + (size_t)R_*10*4)
#define BAR_BOFF   (VT_BOFF + (size_t)N_*B_*2) // 7 counters, 64B apart
#define BAR_BYTES  512

// static LDS pool (byte offsets)
#define ASG_OFF    0            // short[128*LDK]   26,624 B (persistent)
#define WF_OFF     26624        // float[160*72]    46,080 B (persistent)
#define SCR_OFF    72704        // scratch          47,520 B
//   gemm : Bs  short[160*LDK] 33,280 B
//   gtdot: Ast short[80*LDB]  21,760 B ; then LG float[72*165] 47,520 B
#define SMEM_BYTES 120224

typedef __attribute__((ext_vector_type(8))) short short8;
typedef __attribute__((ext_vector_type(4))) float f32x4;

static __device__ __forceinline__ short f2bf(float f) {   // RNE fp32->bf16
    unsigned u = __float_as_uint(f);
    unsigned r = (u + 0x7fffu + ((u >> 16) & 1u)) >> 16;
    return (short)r;
}

// Custom grid barrier: one single-use counter per sync ordinal (zeroed by a
// hipMemsetAsync node before the kernel node in the captured graph).
static __device__ __forceinline__ void gbar(unsigned* __restrict__ bar,
                                            int id, int tid) {
    __syncthreads();   // all waves' global writes issued & vmcnt-drained
    if (tid == 0) {
        unsigned* c = bar + id * 16;          // 64B-spaced counters
        // RELEASE@agent: flush this XCD's dirty L2 lines, then bump.
        __hip_atomic_fetch_add(c, 1u, __ATOMIC_RELEASE,
                               __HIP_MEMORY_SCOPE_AGENT);
        while (__hip_atomic_load(c, __ATOMIC_RELAXED,
                                 __HIP_MEMORY_SCOPE_AGENT) < 256u)
            __builtin_amdgcn_s_sleep(2);
    }
    __syncthreads();
    // ACQUIRE@agent: invalidate stale L1/L2 so we see other XCDs' writes.
    __builtin_amdgcn_fence(__ATOMIC_ACQUIRE, "agent");
}

// ===========================================================================
// Fused cooperative kernel
// ===========================================================================
__global__ __launch_bounds__(256) void k_caps(const float* __restrict__ X,
                                              const float* __restrict__ W,
                                              _Float16* __restrict__ part,
                                              float* __restrict__ bij,
                                              short* __restrict__ vt,
                                              float* __restrict__ out,
                                              unsigned* __restrict__ bar) {
    __shared__ __align__(16) char smem[SMEM_BYTES];
    short* Asg = (short*)(smem + ASG_OFF);   // [b][k] bf16, persistent
    float* Wf  = (float*)(smem + WF_OFF);    // [n=c*16+o][k=rl*8+i] fp32, persistent
    short* Bs  = (short*)(smem + SCR_OFF);   // gemm: scaled W [n][k] bf16
    short* Ast = (short*)(smem + SCR_OFF);   // gtdot: X^T [k][b] bf16
    float* LG  = (float*)(smem + SCR_OFF);   // gtdot: G [72][165] fp32
    __shared__ float cs[90];
    __shared__ float red[40];
    __shared__ float dsm[10];

    const int tid = threadIdx.x;
    const int ks = blockIdx.x >> 1, bt = blockIdx.x & 1;  // == (kt, bh)
    const int b0 = bt * 128, k0 = ks * KB, r0 = ks * 9;

    // ---------------- P0: one-time persistent staging ----------------
    // X[128][72] -> bf16 Asg[b][k]
    #pragma unroll
    for (int j = 0; j < 9; ++j) {
        int q = j * 256 + tid;                     // < 2304
        int bb = q / 18, kf = q - bb * 18;
        float4 a = *(const float4*)(X + (size_t)(b0 + bb) * K_ + k0 + kf * 4);
        short4 h = make_short4(f2bf(a.x), f2bf(a.y), f2bf(a.z), f2bf(a.w));
        *(short4*)(&Asg[bb * LDK + kf * 4]) = h;
    }
    // zero Asg k-pad [72,96)
    #pragma unroll
    for (int j = 0; j < 3; ++j) {
        int q = j * 256 + tid;                     // < 768 = 128*6
        int bb = q / 6, ch = q - bb * 6;
        *(short4*)(&Asg[bb * LDK + 72 + ch * 4]) = make_short4(0, 0, 0, 0);
    }
    // W slice (9 routes) -> fp32 Wf[n][k]
    {
        const float* Wsl = W + (size_t)r0 * 1280;
        #pragma unroll
        for (int j = 0; j < 12; ++j) {
            int q = j * 256 + tid;
            if (q < 2880) {
                int rl = q / 320;
                int rem = q - rl * 320;
                int c = rem >> 5;
                int o = (rem & 31) >> 1;
                int i4 = rem & 1;
                float4 w = *(const float4*)(Wsl + (size_t)q * 4);
                *(float4*)(&Wf[(c * 16 + o) * 72 + rl * 8 + i4 * 4]) = w;
            }
        }
    }
    if (bt == 0 && tid < 90) bij[r0 * 10 + tid] = 0.0f;

    for (int it = 0; it < 3; ++it) {
        // ---------------- coupling coefficients cs[9][10] ----------------
        if (it == 0) {
            if (tid < 90) cs[tid] = 1.0f / 1152.0f;
        } else {
            float dcol[10];
            #pragma unroll
            for (int c = 0; c < 10; ++c) dcol[c] = 0.0f;
            for (int r = tid; r < R_; r += 256) {
                #pragma unroll
                for (int c = 0; c < 10; ++c) dcol[c] += __expf(bij[r * 10 + c]);
            }
            const int lane = tid & 63, wv = tid >> 6;
            #pragma unroll
            for (int c = 0; c < 10; ++c) {
                float s = dcol[c];
                #pragma unroll
                for (int off = 32; off > 0; off >>= 1) s += __shfl_down(s, off);
                if (lane == 0) red[wv * 10 + c] = s;
            }
            __syncthreads();
            if (tid < 10)
                dsm[tid] = red[tid] + red[10 + tid] + red[20 + tid] + red[30 + tid];
            __syncthreads();
            if (tid < 90) {
                int rr = tid / 10, cc = tid - rr * 10;
                cs[tid] = __expf(bij[(r0 + rr) * 10 + cc]) / dsm[cc];
            }
        }
        __syncthreads();   // cs ready (also orders P0 staging on iter 0)

        // ---------------- Bs = (cs ⊙ W) bf16, from LDS fp32 Wf ----------------
        #pragma unroll
        for (int j = 0; j < 12; ++j) {
            int q = j * 256 + tid;
            if (q < 2880) {                         // 160 rows * 18 float4
                int nn = q / 18, kk4 = q - nn * 18;
                float4 w = *(const float4*)(Wf + nn * 72 + kk4 * 4);
                int rl = kk4 >> 1;
                float sc = cs[rl * 10 + (nn >> 4)];
                short4 h = make_short4(f2bf(w.x * sc), f2bf(w.y * sc),
                                       f2bf(w.z * sc), f2bf(w.w * sc));
                *(short4*)(&Bs[nn * LDK + kk4 * 4]) = h;
            }
        }
        #pragma unroll
        for (int j = 0; j < 4; ++j) {
            int q = j * 256 + tid;
            if (q < 960) {                          // 160 rows * 6 pad chunks
                int nn = q / 6, ch = q - nn * 6;
                *(short4*)(&Bs[nn * LDK + 72 + ch * 4]) = make_short4(0, 0, 0, 0);
            }
        }
        __syncthreads();

        // ---------------- GEMM: part[b][ks][n] ----------------
        {
            const int wv = tid >> 6, lane = tid & 63;
            const int lrow = lane & 15, quad = lane >> 4;
            f32x4 acc[2][10];
            #pragma unroll
            for (int mi = 0; mi < 2; ++mi)
                #pragma unroll
                for (int nt = 0; nt < 10; ++nt) acc[mi][nt] = (f32x4)(0.0f);

            #pragma unroll
            for (int ksp = 0; ksp < 3; ++ksp) {
                const int ko = ksp * 32 + quad * 8;
                short8 afr[2], bfr[10];
                #pragma unroll
                for (int mi = 0; mi < 2; ++mi)
                    afr[mi] = *(const short8*)(&Asg[((wv * 2 + mi) * 16 + lrow) * LDK + ko]);
                #pragma unroll
                for (int nt = 0; nt < 10; ++nt)
                    bfr[nt] = *(const short8*)(&Bs[(nt * 16 + lrow) * LDK + ko]);
                #pragma unroll
                for (int mi = 0; mi < 2; ++mi)
                    #pragma unroll
                    for (int nt = 0; nt < 10; ++nt)
                        acc[mi][nt] = __builtin_amdgcn_mfma_f32_16x16x32_bf16(
                            afr[mi], bfr[nt], acc[mi][nt], 0, 0, 0);
            }
            // C store (fp16): row=(quad*4+reg), col=lrow
            #pragma unroll
            for (int mi = 0; mi < 2; ++mi) {
                int bbase = b0 + (wv * 2 + mi) * 16 + quad * 4;
                #pragma unroll
                for (int reg = 0; reg < 4; ++reg) {
                    _Float16* P = part + (size_t)(bbase + reg) * (NS * N_) + ks * N_ + lrow;
                    #pragma unroll
                    for (int nt = 0; nt < 10; ++nt)
                        P[nt * 16] = (_Float16)acc[mi][nt][reg];
                }
            }
        }
        gbar(bar, it * 3 + 0, tid);

        // ---------------- reduce + squash (b = blockIdx.x) ----------------
        if (tid < 160) {
            const int b = blockIdx.x;
            const _Float16* p = part + (size_t)b * (NS * N_) + tid;
            float s = 0.0f;
            #pragma unroll 8
            for (int kk = 0; kk < NS; ++kk) s += (float)p[kk * N_];
            float v = s * fabsf(s) / (1.0f + s * s);   // elementwise squash
            if (it == 2) out[b * N_ + tid] = v;
            else         vt[tid * 256 + b] = f2bf(v);
        }
        if (it == 2) break;
        gbar(bar, it * 3 + 1, tid);

        // ---------- gtdot: G = X^T.V-half, then bij += W·G/B ----------
        // Ast[k][b] from persistent Asg[b][k] (LDS->LDS transpose)
        #pragma unroll
        for (int j = 0; j < 9; ++j) {
            int q = j * 256 + tid;                 // < 2304 = 128*18
            int bb = q / 18, kf = q - bb * 18;
            short4 a = *(const short4*)(&Asg[bb * LDK + kf * 4]);
            Ast[(kf * 4 + 0) * LDB + bb] = a.x;
            Ast[(kf * 4 + 1) * LDB + bb] = a.y;
            Ast[(kf * 4 + 2) * LDB + bb] = a.z;
            Ast[(kf * 4 + 3) * LDB + bb] = a.w;
        }
        __syncthreads();

        {
            const int wv = tid >> 6, lane = tid & 63;
            const int lrow = lane & 15, quad = lane >> 4;
            f32x4 acc[5][3];
            #pragma unroll
            for (int mt = 0; mt < 5; ++mt)
                #pragma unroll
                for (int sl = 0; sl < 3; ++sl) acc[mt][sl] = (f32x4)(0.0f);

            #pragma unroll
            for (int kb = 0; kb < 4; ++kb) {
                const int ko = kb * 32 + quad * 8;
                short8 af[5], bf[3];
                #pragma unroll
                for (int mt = 0; mt < 5; ++mt)
                    af[mt] = *(const short8*)(&Ast[(mt * 16 + lrow) * LDB + ko]);
                // V fragments direct from global vt[n][256b] (L2-resident)
                #pragma unroll
                for (int sl = 0; sl < 3; ++sl) {
                    int nt = wv + sl * 4;
                    if (nt < 10)
                        bf[sl] = *(const short8*)(vt + (nt * 16 + lrow) * 256 + b0 + ko);
                }
                #pragma unroll
                for (int mt = 0; mt < 5; ++mt)
                    #pragma unroll
                    for (int sl = 0; sl < 3; ++sl)
                        if (wv + sl * 4 < 10)
                            acc[mt][sl] = __builtin_amdgcn_mfma_f32_16x16x32_bf16(
                                af[mt], bf[sl], acc[mt][sl], 0, 0, 0);
            }
            __syncthreads();   // frag reads done; reuse scratch as LG

            #pragma unroll
            for (int mt = 0; mt < 5; ++mt) {
                #pragma unroll
                for (int sl = 0; sl < 3; ++sl) {
                    int nt = wv + sl * 4;
                    if (nt < 10) {
                        #pragma unroll
                        for (int reg = 0; reg < 4; ++reg) {
                            int m = mt * 16 + quad * 4 + reg;
                            if (m < 72)
                                LG[m * 165 + nt * 16 + lrow] = acc[mt][sl][reg];
                        }
                    }
                }
            }
        }
        __syncthreads();
        // per-route dot with W (fp32 from LDS), atomicAdd into bij
        if (tid < 90) {
            int rl = tid / 10, c = tid - rl * 10;
            int r = r0 + rl;
            const float* wbase = Wf + (c * 16) * 72 + rl * 8;
            float s = 0.0f;
            #pragma unroll
            for (int o = 0; o < 16; ++o) {
                const float* wp = wbase + o * 72;
                float4 wa = *(const float4*)(wp);
                float4 wb = *(const float4*)(wp + 4);
                const float* g = &LG[(rl * 8) * 165 + c * 16 + o];
                s += wa.x * g[0]       + wa.y * g[165]     + wa.z * g[2 * 165] +
                     wa.w * g[3 * 165] + wb.x * g[4 * 165] + wb.y * g[5 * 165] +
                     wb.z * g[6 * 165] + wb.w * g[7 * 165];
            }
            atomicAdd(&bij[r * 10 + c], s * (1.0f / B_));
        }
        gbar(bar, it * 3 + 2, tid);
    }
}

// ===========================================================================
// Fallback path: verified R13 kernels (131.9 us) — used only if the
// cooperative launch is rejected. Guarantees no silent-zero failure.
// ===========================================================================
__global__ __launch_bounds__(256) void k_gemm(const float* __restrict__ X,
                                              const float* __restrict__ W,
                                              float* __restrict__ bij,
                                              _Float16* __restrict__ part,
                                              int it) {
    __shared__ short As[128 * LDK];
    __shared__ short BsF[160 * LDK];
    __shared__ float cs[90];
    __shared__ float red[40];
    __shared__ float dsm[10];
    const int tid = threadIdx.x;
    const int ks = blockIdx.x >> 1, bt = blockIdx.x & 1;
    const int b0 = bt * 128, k0 = ks * KB, r0 = ks * 9;

    if (it == 0) {
        if (tid < 90) cs[tid] = 1.0f / 1152.0f;
        if (bt == 0 && tid < 90) bij[r0 * 10 + tid] = 0.0f;
    } else {
        float dcol[10];
        #pragma unroll
        for (int c = 0; c < 10; ++c) dcol[c] = 0.0f;
        for (int r = tid; r < R_; r += 256) {
            #pragma unroll
            for (int c = 0; c < 10; ++c) dcol[c] += __expf(bij[r * 10 + c]);
        }
        const int lane = tid & 63, wv = tid >> 6;
        #pragma unroll
        for (int c = 0; c < 10; ++c) {
            float s = dcol[c];
            #pragma unroll
            for (int off = 32; off > 0; off >>= 1) s += __shfl_down(s, off);
            if (lane == 0) red[wv * 10 + c] = s;
        }
        __syncthreads();
        if (tid < 10)
            dsm[tid] = red[tid] + red[10 + tid] + red[20 + tid] + red[30 + tid];
        __syncthreads();
        if (tid < 90) {
            int rr = tid / 10, cc = tid - rr * 10;
            cs[tid] = __expf(bij[(r0 + rr) * 10 + cc]) / dsm[cc];
        }
    }

    #pragma unroll
    for (int j = 0; j < 9; ++j) {
        int q = j * 256 + tid;
        int bb = q / 18, kf = q - bb * 18;
        float4 a = *(const float4*)(X + (size_t)(b0 + bb) * K_ + k0 + kf * 4);
        short4 h = make_short4(f2bf(a.x), f2bf(a.y), f2bf(a.z), f2bf(a.w));
        *(short4*)(&As[bb * LDK + kf * 4]) = h;
    }
    #pragma unroll
    for (int j = 0; j < 3; ++j) {
        int q = j * 256 + tid;
        int bb = q / 6, ch = q - bb * 6;
        *(short4*)(&As[bb * LDK + 72 + ch * 4]) = make_short4(0, 0, 0, 0);
    }
    {
        const float* Wsl = W + (size_t)r0 * 1280;
        #pragma unroll
        for (int j = 0; j < 12; ++j) {
            int q = j * 256 + tid;
            if (q < 2880) {
                int rl = q / 320;
                int rem = q - rl * 320;
                int c = rem >> 5;
                int o = (rem & 31) >> 1;
                int i4 = rem & 1;
                float4 w = *(const float4*)(Wsl + (size_t)q * 4);
                float sc = cs[rl * 10 + c];
                int nn = c * 16 + o;
                int kk = rl * 8 + i4 * 4;
                short4 h = make_short4(f2bf(w.x * sc), f2bf(w.y * sc),
                                       f2bf(w.z * sc), f2bf(w.w * sc));
                *(short4*)(&BsF[nn * LDK + kk]) = h;
            }
        }
        #pragma unroll
        for (int j = 0; j < 4; ++j) {
            int q = j * 256 + tid;
            if (q < 960) {
                int nn = q / 6, ch = q - nn * 6;
                *(short4*)(&BsF[nn * LDK + 72 + ch * 4]) = make_short4(0, 0, 0, 0);
            }
        }
    }
    __syncthreads();

    const int wv = tid >> 6, lane = tid & 63;
    const int lrow = lane & 15, quad = lane >> 4;
    f32x4 acc[2][10];
    #pragma unroll
    for (int mi = 0; mi < 2; ++mi)
        #pragma unroll
        for (int nt = 0; nt < 10; ++nt) acc[mi][nt] = (f32x4)(0.0f);

    #pragma unroll
    for (int ksp = 0; ksp < 3; ++ksp) {
        const int ko = ksp * 32 + quad * 8;
        short8 afr[2], bfr[10];
        #pragma unroll
        for (int mi = 0; mi < 2; ++mi)
            afr[mi] = *(const short8*)(&As[((wv * 2 + mi) * 16 + lrow) * LDK + ko]);
        #pragma unroll
        for (int nt = 0; nt < 10; ++nt)
            bfr[nt] = *(const short8*)(&BsF[(nt * 16 + lrow) * LDK + ko]);
        #pragma unroll
        for (int mi = 0; mi < 2; ++mi)
            #pragma unroll
            for (int nt = 0; nt < 10; ++nt)
                acc[mi][nt] = __builtin_amdgcn_mfma_f32_16x16x32_bf16(
                    afr[mi], bfr[nt], acc[mi][nt], 0, 0, 0);
    }

    #pragma unroll
    for (int mi = 0; mi < 2; ++mi) {
        int bbase = b0 + (wv * 2 + mi) * 16 + quad * 4;
        #pragma unroll
        for (int reg = 0; reg < 4; ++reg) {
            _Float16* P = part + (size_t)(bbase + reg) * (NS * N_) + ks * N_ + lrow;
            #pragma unroll
            for (int nt = 0; nt < 10; ++nt)
                P[nt * 16] = (_Float16)acc[mi][nt][reg];
        }
    }
}

__global__ void k_reduce(const _Float16* __restrict__ part,
                         float* __restrict__ out,
                         short* __restrict__ vt, int fin) {
    const int n = threadIdx.x, b = blockIdx.x;
    if (n < 160) {
        const _Float16* p = part + (size_t)b * (NS * N_) + n;
        float s = 0.0f;
        #pragma unroll 8
        for (int ks = 0; ks < NS; ++ks) s += (float)p[ks * N_];
        float v = s * fabsf(s) / (1.0f + s * s);
        if (fin) out[b * N_ + n] = v;
        else     vt[n * 256 + b] = f2bf(v);
    }
}

__global__ __launch_bounds__(256) void k_gtdot(const float* __restrict__ X,
                                               const float* __restrict__ W,
                                               const short* __restrict__ Vt,
                                               float* __restrict__ bij) {
    __shared__ short SM2[32640];
    short* As = SM2;
    short* Bs2 = SM2 + 80 * LDB;
    float* LG = (float*)SM2;
    const int tid = threadIdx.x;
    const int kt = blockIdx.x >> 1, bh = blockIdx.x & 1;
    const int k0 = kt * 72, r0 = kt * 9, b0 = bh * 128;

    #pragma unroll
    for (int j = 0; j < 9; ++j) {
        int q = j * 256 + tid;
        int bb = q / 18, kf = q - bb * 18;
        float4 a = *(const float4*)(X + (size_t)(b0 + bb) * K_ + k0 + kf * 4);
        As[(kf * 4 + 0) * LDB + bb] = f2bf(a.x);
        As[(kf * 4 + 1) * LDB + bb] = f2bf(a.y);
        As[(kf * 4 + 2) * LDB + bb] = f2bf(a.z);
        As[(kf * 4 + 3) * LDB + bb] = f2bf(a.w);
    }
    #pragma unroll
    for (int j = 0; j < 10; ++j) {
        int q = j * 256 + tid;
        int n = q >> 4, s = q & 15;
        *(short8*)(&Bs2[n * LDB + s * 8]) =
            *(const short8*)(Vt + n * 256 + b0 + s * 8);
    }
    __syncthreads();

    const int wv = tid >> 6, lane = tid & 63;
    const int lrow = lane & 15, quad = lane >> 4;
    f32x4 acc[5][3];
    #pragma unroll
    for (int mt = 0; mt < 5; ++mt)
        #pragma unroll
        for (int sl = 0; sl < 3; ++sl) acc[mt][sl] = (f32x4)(0.0f);

    #pragma unroll
    for (int kb = 0; kb < 4; ++kb) {
        const int ko = kb * 32 + quad * 8;
        short8 af[5], bf[3];
        #pragma unroll
        for (int mt = 0; mt < 5; ++mt)
            af[mt] = *(const short8*)(&As[(mt * 16 + lrow) * LDB + ko]);
        #pragma unroll
        for (int sl = 0; sl < 3; ++sl) {
            int nt = wv + sl * 4;
            if (nt < 10)
                bf[sl] = *(const short8*)(&Bs2[(nt * 16 + lrow) * LDB + ko]);
        }
        #pragma unroll
        for (int mt = 0; mt < 5; ++mt)
            #pragma unroll
            for (int sl = 0; sl < 3; ++sl)
                if (wv + sl * 4 < 10)
                    acc[mt][sl] = __builtin_amdgcn_mfma_f32_16x16x32_bf16(
                        af[mt], bf[sl], acc[mt][sl], 0, 0, 0);
    }
    __syncthreads();

    #pragma unroll
    for (int mt = 0; mt < 5; ++mt) {
        #pragma unroll
        for (int sl = 0; sl < 3; ++sl) {
            int nt = wv + sl * 4;
            if (nt < 10) {
                #pragma unroll
                for (int reg = 0; reg < 4; ++reg) {
                    int m = mt * 16 + quad * 4 + reg;
                    if (m < 72)
                        LG[m * 165 + nt * 16 + lrow] = acc[mt][sl][reg];
                }
            }
        }
    }
    __syncthreads();
    if (tid < 90) {
        int rl = tid / 10, c = tid - rl * 10;
        int r = r0 + rl;
        const float4* wp = (const float4*)(W + (size_t)r * 1280 + c * 128);
        float s = 0.0f;
        #pragma unroll
        for (int o = 0; o < 16; ++o) {
            float4 wa = wp[o * 2], wb = wp[o * 2 + 1];
            const float* g = &LG[(rl * 8) * 165 + c * 16 + o];
            s += wa.x * g[0]       + wa.y * g[165]     + wa.z * g[2 * 165] +
                 wa.w * g[3 * 165] + wb.x * g[4 * 165] + wb.y * g[5 * 165] +
                 wb.z * g[6 * 165] + wb.w * g[7 * 165];
        }
        atomicAdd(&bij[r * 10 + c], s * (1.0f / B_));
    }
}

// ---------------------------------------------------------------------------
extern "C" void kernel_launch(void* const* d_in, const int* in_sizes, int n_in,
                              void* d_out, int out_size, void* d_ws, size_t ws_size,
                              hipStream_t stream) {
    const float* x = (const float*)d_in[0];   // (256, 1152, 8)
    const float* W = (const float*)d_in[1];   // (1152, 10, 16, 8)
    char* ws       = (char*)d_ws;
    _Float16* part = (_Float16*)ws;
    float* bij     = (float*)(ws + BIJ_BOFF);
    short* vt      = (short*)(ws + VT_BOFF);  // Vt[160][256] bf16
    unsigned* bar  = (unsigned*)(ws + BAR_BOFF);
    float* outf    = (float*)d_out;

    // zero the 7 single-use barrier counters (captured as a graph node, so
    // every replay re-arms them)
    hipMemsetAsync((void*)bar, 0, BAR_BYTES, stream);

    void* args[] = {(void*)&x, (void*)&W, (void*)&part,
                    (void*)&bij, (void*)&vt, (void*)&outf, (void*)&bar};
    hipError_t e = hipLaunchCooperativeKernel((const void*)k_caps, dim3(256),
                                              dim3(256), args, 0, stream);
    if (e != hipSuccess) {
        // fallback: verified 8-dispatch path
        for (int it = 0; it < 3; ++it) {
            k_gemm<<<256, 256, 0, stream>>>(x, W, bij, part, it);
            k_reduce<<<256, 256, 0, stream>>>(part, outf, vt, it == 2);
            if (it < 2) k_gtdot<<<256, 256, 0, stream>>>(x, W, vt, bij);
        }
    }
}

// Round 4
// 275.579 us; speedup vs baseline: 2.1934x; 1.4035x over previous
//
#include <hip/hip_runtime.h>
#include <math.h>

// DigitCaps dynamic routing. B=256, R=1152, C=10, O=16, I=8, 3 iters.
// R17: leader-flush grid barrier. R16's barrier (~35us each) had ALL 256
// blocks issue agent-scope release/acquire fences => 32 concurrent
// buffer_wbl2 + buffer_inv L2 walks per XCD, serialized at each L2.
// New barrier: relaxed-atomic arrive (no cache ops), ONE leader per XCD
// (s_getreg XCC_ID) does the single wbl2+inv for its L2 (8 grid-wide ==
// what a kernel boundary does), everyone spins done==8, then per-wave
// workgroup-acquire (L1 inv only). Dataflow/numerics identical to
// R15/R16 (passed, absmax 4.9e-4). Fallback: verified R13 path.

#define B_ 256
#define R_ 1152
#define N_ 160      // C*O
#define K_ 9216     // R*I
#define NS 128      // K splits of 72 (9 routes)
#define KB 72
#define LDK 104     // gemm LDS k-stride (bf16 elems)
#define LDB 136     // gtdot LDS b-stride (bf16 elems)

// workspace layout (byte offsets)
#define PART_ELEMS ((size_t)B_*NS*N_)          // 5,242,880 fp16 = 10.49 MB
#define BIJ_BOFF   (PART_ELEMS*2)
#define VT_BOFF    (BIJ_BOFF + (size_t)R_*10*4)
#define BAR_BOFF   (VT_BOFF + (size_t)N_*B_*2) // 7 ordinals x 256B
#define BAR_BYTES  2048

// static LDS pool (byte offsets)
#define ASG_OFF    0            // short[128*LDK]   26,624 B (persistent)
#define WF_OFF     26624        // float[160*72]    46,080 B (persistent)
#define SCR_OFF    72704        // scratch          47,520 B
//   gemm : Bs  short[160*LDK] 33,280 B
//   gtdot: Ast short[80*LDB]  21,760 B ; then LG float[72*165] 47,520 B
#define SMEM_BYTES 120224

typedef __attribute__((ext_vector_type(8))) short short8;
typedef __attribute__((ext_vector_type(4))) float f32x4;

static __device__ __forceinline__ short f2bf(float f) {   // RNE fp32->bf16
    unsigned u = __float_as_uint(f);
    unsigned r = (u + 0x7fffu + ((u >> 16) & 1u)) >> 16;
    return (short)r;
}

// Leader-flush grid barrier. Per ordinal (256B): claim[8] @ +0 (one per
// XCD), arrive @ +64B, done @ +128B. All counters zeroed by hipMemsetAsync
// before the kernel node (re-armed on every graph replay).
static __device__ __forceinline__ void gbar(unsigned* __restrict__ bar,
                                            int id, int tid) {
    __syncthreads();   // all waves' global stores vmcnt-drained into L2
    if (tid == 0) {
        unsigned* base = bar + id * 64;       // 64 dwords = 256B per ordinal
        unsigned xcd;
        asm volatile("s_getreg_b32 %0, hwreg(HW_REG_XCC_ID)" : "=s"(xcd));
        xcd &= 7;
        // leader election for this XCD (relaxed: election only)
        bool lead = (__hip_atomic_fetch_add(base + xcd, 1u, __ATOMIC_RELAXED,
                                            __HIP_MEMORY_SCOPE_AGENT) == 0u);
        // arrive: stores already drained to local L2 by the __syncthreads
        __hip_atomic_fetch_add(base + 16, 1u, __ATOMIC_RELAXED,
                               __HIP_MEMORY_SCOPE_AGENT);
        if (lead) {
            while (__hip_atomic_load(base + 16, __ATOMIC_RELAXED,
                                     __HIP_MEMORY_SCOPE_AGENT) < 256u)
                __builtin_amdgcn_s_sleep(1);
            // exactly ONE wbl2 + ONE inv per XCD L2 (kernel-boundary cost)
            __builtin_amdgcn_fence(__ATOMIC_RELEASE, "agent"); // wbl2: flush
            __builtin_amdgcn_fence(__ATOMIC_ACQUIRE, "agent"); // inv: refresh
            __hip_atomic_fetch_add(base + 32, 1u, __ATOMIC_RELAXED,
                                   __HIP_MEMORY_SCOPE_AGENT);
        }
        while (__hip_atomic_load(base + 32, __ATOMIC_RELAXED,
                                 __HIP_MEMORY_SCOPE_AGENT) < 8u)
            __builtin_amdgcn_s_sleep(1);
    }
    __syncthreads();
    // per-CU L1 invalidate so post-barrier loads can't hit stale lines
    __builtin_amdgcn_fence(__ATOMIC_ACQUIRE, "workgroup");
}

// ===========================================================================
// Fused cooperative kernel
// ===========================================================================
__global__ __launch_bounds__(256) void k_caps(const float* __restrict__ X,
                                              const float* __restrict__ W,
                                              _Float16* __restrict__ part,
                                              float* __restrict__ bij,
                                              short* __restrict__ vt,
                                              float* __restrict__ out,
                                              unsigned* __restrict__ bar) {
    __shared__ __align__(16) char smem[SMEM_BYTES];
    short* Asg = (short*)(smem + ASG_OFF);   // [b][k] bf16, persistent
    float* Wf  = (float*)(smem + WF_OFF);    // [n=c*16+o][k=rl*8+i] fp32, persistent
    short* Bs  = (short*)(smem + SCR_OFF);   // gemm: scaled W [n][k] bf16
    short* Ast = (short*)(smem + SCR_OFF);   // gtdot: X^T [k][b] bf16
    float* LG  = (float*)(smem + SCR_OFF);   // gtdot: G [72][165] fp32
    __shared__ float cs[90];
    __shared__ float red[40];
    __shared__ float dsm[10];

    const int tid = threadIdx.x;
    const int ks = blockIdx.x >> 1, bt = blockIdx.x & 1;  // == (kt, bh)
    const int b0 = bt * 128, k0 = ks * KB, r0 = ks * 9;

    // ---------------- P0: one-time persistent staging ----------------
    // X[128][72] -> bf16 Asg[b][k]
    #pragma unroll
    for (int j = 0; j < 9; ++j) {
        int q = j * 256 + tid;                     // < 2304
        int bb = q / 18, kf = q - bb * 18;
        float4 a = *(const float4*)(X + (size_t)(b0 + bb) * K_ + k0 + kf * 4);
        short4 h = make_short4(f2bf(a.x), f2bf(a.y), f2bf(a.z), f2bf(a.w));
        *(short4*)(&Asg[bb * LDK + kf * 4]) = h;
    }
    // zero Asg k-pad [72,96)
    #pragma unroll
    for (int j = 0; j < 3; ++j) {
        int q = j * 256 + tid;                     // < 768 = 128*6
        int bb = q / 6, ch = q - bb * 6;
        *(short4*)(&Asg[bb * LDK + 72 + ch * 4]) = make_short4(0, 0, 0, 0);
    }
    // W slice (9 routes) -> fp32 Wf[n][k]
    {
        const float* Wsl = W + (size_t)r0 * 1280;
        #pragma unroll
        for (int j = 0; j < 12; ++j) {
            int q = j * 256 + tid;
            if (q < 2880) {
                int rl = q / 320;
                int rem = q - rl * 320;
                int c = rem >> 5;
                int o = (rem & 31) >> 1;
                int i4 = rem & 1;
                float4 w = *(const float4*)(Wsl + (size_t)q * 4);
                *(float4*)(&Wf[(c * 16 + o) * 72 + rl * 8 + i4 * 4]) = w;
            }
        }
    }
    if (bt == 0 && tid < 90) bij[r0 * 10 + tid] = 0.0f;

    for (int it = 0; it < 3; ++it) {
        // ---------------- coupling coefficients cs[9][10] ----------------
        if (it == 0) {
            if (tid < 90) cs[tid] = 1.0f / 1152.0f;
        } else {
            float dcol[10];
            #pragma unroll
            for (int c = 0; c < 10; ++c) dcol[c] = 0.0f;
            for (int r = tid; r < R_; r += 256) {
                #pragma unroll
                for (int c = 0; c < 10; ++c) dcol[c] += __expf(bij[r * 10 + c]);
            }
            const int lane = tid & 63, wv = tid >> 6;
            #pragma unroll
            for (int c = 0; c < 10; ++c) {
                float s = dcol[c];
                #pragma unroll
                for (int off = 32; off > 0; off >>= 1) s += __shfl_down(s, off);
                if (lane == 0) red[wv * 10 + c] = s;
            }
            __syncthreads();
            if (tid < 10)
                dsm[tid] = red[tid] + red[10 + tid] + red[20 + tid] + red[30 + tid];
            __syncthreads();
            if (tid < 90) {
                int rr = tid / 10, cc = tid - rr * 10;
                cs[tid] = __expf(bij[(r0 + rr) * 10 + cc]) / dsm[cc];
            }
        }
        __syncthreads();   // cs ready (also orders P0 staging on iter 0)

        // ---------------- Bs = (cs ⊙ W) bf16, from LDS fp32 Wf ----------------
        #pragma unroll
        for (int j = 0; j < 12; ++j) {
            int q = j * 256 + tid;
            if (q < 2880) {                         // 160 rows * 18 float4
                int nn = q / 18, kk4 = q - nn * 18;
                float4 w = *(const float4*)(Wf + nn * 72 + kk4 * 4);
                int rl = kk4 >> 1;
                float sc = cs[rl * 10 + (nn >> 4)];
                short4 h = make_short4(f2bf(w.x * sc), f2bf(w.y * sc),
                                       f2bf(w.z * sc), f2bf(w.w * sc));
                *(short4*)(&Bs[nn * LDK + kk4 * 4]) = h;
            }
        }
        #pragma unroll
        for (int j = 0; j < 4; ++j) {
            int q = j * 256 + tid;
            if (q < 960) {                          // 160 rows * 6 pad chunks
                int nn = q / 6, ch = q - nn * 6;
                *(short4*)(&Bs[nn * LDK + 72 + ch * 4]) = make_short4(0, 0, 0, 0);
            }
        }
        __syncthreads();

        // ---------------- GEMM: part[b][ks][n] ----------------
        {
            const int wv = tid >> 6, lane = tid & 63;
            const int lrow = lane & 15, quad = lane >> 4;
            f32x4 acc[2][10];
            #pragma unroll
            for (int mi = 0; mi < 2; ++mi)
                #pragma unroll
                for (int nt = 0; nt < 10; ++nt) acc[mi][nt] = (f32x4)(0.0f);

            #pragma unroll
            for (int ksp = 0; ksp < 3; ++ksp) {
                const int ko = ksp * 32 + quad * 8;
                short8 afr[2], bfr[10];
                #pragma unroll
                for (int mi = 0; mi < 2; ++mi)
                    afr[mi] = *(const short8*)(&Asg[((wv * 2 + mi) * 16 + lrow) * LDK + ko]);
                #pragma unroll
                for (int nt = 0; nt < 10; ++nt)
                    bfr[nt] = *(const short8*)(&Bs[(nt * 16 + lrow) * LDK + ko]);
                #pragma unroll
                for (int mi = 0; mi < 2; ++mi)
                    #pragma unroll
                    for (int nt = 0; nt < 10; ++nt)
                        acc[mi][nt] = __builtin_amdgcn_mfma_f32_16x16x32_bf16(
                            afr[mi], bfr[nt], acc[mi][nt], 0, 0, 0);
            }
            // C store (fp16): row=(quad*4+reg), col=lrow
            #pragma unroll
            for (int mi = 0; mi < 2; ++mi) {
                int bbase = b0 + (wv * 2 + mi) * 16 + quad * 4;
                #pragma unroll
                for (int reg = 0; reg < 4; ++reg) {
                    _Float16* P = part + (size_t)(bbase + reg) * (NS * N_) + ks * N_ + lrow;
                    #pragma unroll
                    for (int nt = 0; nt < 10; ++nt)
                        P[nt * 16] = (_Float16)acc[mi][nt][reg];
                }
            }
        }
        gbar(bar, it * 3 + 0, tid);

        // ---------------- reduce + squash (b = blockIdx.x) ----------------
        if (tid < 160) {
            const int b = blockIdx.x;
            const _Float16* p = part + (size_t)b * (NS * N_) + tid;
            float s = 0.0f;
            #pragma unroll 8
            for (int kk = 0; kk < NS; ++kk) s += (float)p[kk * N_];
            float v = s * fabsf(s) / (1.0f + s * s);   // elementwise squash
            if (it == 2) out[b * N_ + tid] = v;
            else         vt[tid * 256 + b] = f2bf(v);
        }
        if (it == 2) break;
        gbar(bar, it * 3 + 1, tid);

        // ---------- gtdot: G = X^T.V-half, then bij += W·G/B ----------
        // Ast[k][b] from persistent Asg[b][k] (LDS->LDS transpose)
        #pragma unroll
        for (int j = 0; j < 9; ++j) {
            int q = j * 256 + tid;                 // < 2304 = 128*18
            int bb = q / 18, kf = q - bb * 18;
            short4 a = *(const short4*)(&Asg[bb * LDK + kf * 4]);
            Ast[(kf * 4 + 0) * LDB + bb] = a.x;
            Ast[(kf * 4 + 1) * LDB + bb] = a.y;
            Ast[(kf * 4 + 2) * LDB + bb] = a.z;
            Ast[(kf * 4 + 3) * LDB + bb] = a.w;
        }
        __syncthreads();

        {
            const int wv = tid >> 6, lane = tid & 63;
            const int lrow = lane & 15, quad = lane >> 4;
            f32x4 acc[5][3];
            #pragma unroll
            for (int mt = 0; mt < 5; ++mt)
                #pragma unroll
                for (int sl = 0; sl < 3; ++sl) acc[mt][sl] = (f32x4)(0.0f);

            #pragma unroll
            for (int kb = 0; kb < 4; ++kb) {
                const int ko = kb * 32 + quad * 8;
                short8 af[5], bf[3];
                #pragma unroll
                for (int mt = 0; mt < 5; ++mt)
                    af[mt] = *(const short8*)(&Ast[(mt * 16 + lrow) * LDB + ko]);
                // V fragments direct from global vt[n][256b] (L2-resident)
                #pragma unroll
                for (int sl = 0; sl < 3; ++sl) {
                    int nt = wv + sl * 4;
                    if (nt < 10)
                        bf[sl] = *(const short8*)(vt + (nt * 16 + lrow) * 256 + b0 + ko);
                }
                #pragma unroll
                for (int mt = 0; mt < 5; ++mt)
                    #pragma unroll
                    for (int sl = 0; sl < 3; ++sl)
                        if (wv + sl * 4 < 10)
                            acc[mt][sl] = __builtin_amdgcn_mfma_f32_16x16x32_bf16(
                                af[mt], bf[sl], acc[mt][sl], 0, 0, 0);
            }
            __syncthreads();   // frag reads done; reuse scratch as LG

            #pragma unroll
            for (int mt = 0; mt < 5; ++mt) {
                #pragma unroll
                for (int sl = 0; sl < 3; ++sl) {
                    int nt = wv + sl * 4;
                    if (nt < 10) {
                        #pragma unroll
                        for (int reg = 0; reg < 4; ++reg) {
                            int m = mt * 16 + quad * 4 + reg;
                            if (m < 72)
                                LG[m * 165 + nt * 16 + lrow] = acc[mt][sl][reg];
                        }
                    }
                }
            }
        }
        __syncthreads();
        // per-route dot with W (fp32 from LDS), atomicAdd into bij
        if (tid < 90) {
            int rl = tid / 10, c = tid - rl * 10;
            int r = r0 + rl;
            const float* wbase = Wf + (c * 16) * 72 + rl * 8;
            float s = 0.0f;
            #pragma unroll
            for (int o = 0; o < 16; ++o) {
                const float* wp = wbase + o * 72;
                float4 wa = *(const float4*)(wp);
                float4 wb = *(const float4*)(wp + 4);
                const float* g = &LG[(rl * 8) * 165 + c * 16 + o];
                s += wa.x * g[0]       + wa.y * g[165]     + wa.z * g[2 * 165] +
                     wa.w * g[3 * 165] + wb.x * g[4 * 165] + wb.y * g[5 * 165] +
                     wb.z * g[6 * 165] + wb.w * g[7 * 165];
            }
            atomicAdd(&bij[r * 10 + c], s * (1.0f / B_));
        }
        gbar(bar, it * 3 + 2, tid);
    }
}

// ===========================================================================
// Fallback path: verified R13 kernels (131.9 us) — used only if the
// cooperative launch is rejected. Guarantees no silent-zero failure.
// ===========================================================================
__global__ __launch_bounds__(256) void k_gemm(const float* __restrict__ X,
                                              const float* __restrict__ W,
                                              float* __restrict__ bij,
                                              _Float16* __restrict__ part,
                                              int it) {
    __shared__ short As[128 * LDK];
    __shared__ short BsF[160 * LDK];
    __shared__ float cs[90];
    __shared__ float red[40];
    __shared__ float dsm[10];
    const int tid = threadIdx.x;
    const int ks = blockIdx.x >> 1, bt = blockIdx.x & 1;
    const int b0 = bt * 128, k0 = ks * KB, r0 = ks * 9;

    if (it == 0) {
        if (tid < 90) cs[tid] = 1.0f / 1152.0f;
        if (bt == 0 && tid < 90) bij[r0 * 10 + tid] = 0.0f;
    } else {
        float dcol[10];
        #pragma unroll
        for (int c = 0; c < 10; ++c) dcol[c] = 0.0f;
        for (int r = tid; r < R_; r += 256) {
            #pragma unroll
            for (int c = 0; c < 10; ++c) dcol[c] += __expf(bij[r * 10 + c]);
        }
        const int lane = tid & 63, wv = tid >> 6;
        #pragma unroll
        for (int c = 0; c < 10; ++c) {
            float s = dcol[c];
            #pragma unroll
            for (int off = 32; off > 0; off >>= 1) s += __shfl_down(s, off);
            if (lane == 0) red[wv * 10 + c] = s;
        }
        __syncthreads();
        if (tid < 10)
            dsm[tid] = red[tid] + red[10 + tid] + red[20 + tid] + red[30 + tid];
        __syncthreads();
        if (tid < 90) {
            int rr = tid / 10, cc = tid - rr * 10;
            cs[tid] = __expf(bij[(r0 + rr) * 10 + cc]) / dsm[cc];
        }
    }

    #pragma unroll
    for (int j = 0; j < 9; ++j) {
        int q = j * 256 + tid;
        int bb = q / 18, kf = q - bb * 18;
        float4 a = *(const float4*)(X + (size_t)(b0 + bb) * K_ + k0 + kf * 4);
        short4 h = make_short4(f2bf(a.x), f2bf(a.y), f2bf(a.z), f2bf(a.w));
        *(short4*)(&As[bb * LDK + kf * 4]) = h;
    }
    #pragma unroll
    for (int j = 0; j < 3; ++j) {
        int q = j * 256 + tid;
        int bb = q / 6, ch = q - bb * 6;
        *(short4*)(&As[bb * LDK + 72 + ch * 4]) = make_short4(0, 0, 0, 0);
    }
    {
        const float* Wsl = W + (size_t)r0 * 1280;
        #pragma unroll
        for (int j = 0; j < 12; ++j) {
            int q = j * 256 + tid;
            if (q < 2880) {
                int rl = q / 320;
                int rem = q - rl * 320;
                int c = rem >> 5;
                int o = (rem & 31) >> 1;
                int i4 = rem & 1;
                float4 w = *(const float4*)(Wsl + (size_t)q * 4);
                float sc = cs[rl * 10 + c];
                int nn = c * 16 + o;
                int kk = rl * 8 + i4 * 4;
                short4 h = make_short4(f2bf(w.x * sc), f2bf(w.y * sc),
                                       f2bf(w.z * sc), f2bf(w.w * sc));
                *(short4*)(&BsF[nn * LDK + kk]) = h;
            }
        }
        #pragma unroll
        for (int j = 0; j < 4; ++j) {
            int q = j * 256 + tid;
            if (q < 960) {
                int nn = q / 6, ch = q - nn * 6;
                *(short4*)(&BsF[nn * LDK + 72 + ch * 4]) = make_short4(0, 0, 0, 0);
            }
        }
    }
    __syncthreads();

    const int wv = tid >> 6, lane = tid & 63;
    const int lrow = lane & 15, quad = lane >> 4;
    f32x4 acc[2][10];
    #pragma unroll
    for (int mi = 0; mi < 2; ++mi)
        #pragma unroll
        for (int nt = 0; nt < 10; ++nt) acc[mi][nt] = (f32x4)(0.0f);

    #pragma unroll
    for (int ksp = 0; ksp < 3; ++ksp) {
        const int ko = ksp * 32 + quad * 8;
        short8 afr[2], bfr[10];
        #pragma unroll
        for (int mi = 0; mi < 2; ++mi)
            afr[mi] = *(const short8*)(&As[((wv * 2 + mi) * 16 + lrow) * LDK + ko]);
        #pragma unroll
        for (int nt = 0; nt < 10; ++nt)
            bfr[nt] = *(const short8*)(&BsF[(nt * 16 + lrow) * LDK + ko]);
        #pragma unroll
        for (int mi = 0; mi < 2; ++mi)
            #pragma unroll
            for (int nt = 0; nt < 10; ++nt)
                acc[mi][nt] = __builtin_amdgcn_mfma_f32_16x16x32_bf16(
                    afr[mi], bfr[nt], acc[mi][nt], 0, 0, 0);
    }

    #pragma unroll
    for (int mi = 0; mi < 2; ++mi) {
        int bbase = b0 + (wv * 2 + mi) * 16 + quad * 4;
        #pragma unroll
        for (int reg = 0; reg < 4; ++reg) {
            _Float16* P = part + (size_t)(bbase + reg) * (NS * N_) + ks * N_ + lrow;
            #pragma unroll
            for (int nt = 0; nt < 10; ++nt)
                P[nt * 16] = (_Float16)acc[mi][nt][reg];
        }
    }
}

__global__ void k_reduce(const _Float16* __restrict__ part,
                         float* __restrict__ out,
                         short* __restrict__ vt, int fin) {
    const int n = threadIdx.x, b = blockIdx.x;
    if (n < 160) {
        const _Float16* p = part + (size_t)b * (NS * N_) + n;
        float s = 0.0f;
        #pragma unroll 8
        for (int ks = 0; ks < NS; ++ks) s += (float)p[ks * N_];
        float v = s * fabsf(s) / (1.0f + s * s);
        if (fin) out[b * N_ + n] = v;
        else     vt[n * 256 + b] = f2bf(v);
    }
}

__global__ __launch_bounds__(256) void k_gtdot(const float* __restrict__ X,
                                               const float* __restrict__ W,
                                               const short* __restrict__ Vt,
                                               float* __restrict__ bij) {
    __shared__ short SM2[32640];
    short* As = SM2;
    short* Bs2 = SM2 + 80 * LDB;
    float* LG = (float*)SM2;
    const int tid = threadIdx.x;
    const int kt = blockIdx.x >> 1, bh = blockIdx.x & 1;
    const int k0 = kt * 72, r0 = kt * 9, b0 = bh * 128;

    #pragma unroll
    for (int j = 0; j < 9; ++j) {
        int q = j * 256 + tid;
        int bb = q / 18, kf = q - bb * 18;
        float4 a = *(const float4*)(X + (size_t)(b0 + bb) * K_ + k0 + kf * 4);
        As[(kf * 4 + 0) * LDB + bb] = f2bf(a.x);
        As[(kf * 4 + 1) * LDB + bb] = f2bf(a.y);
        As[(kf * 4 + 2) * LDB + bb] = f2bf(a.z);
        As[(kf * 4 + 3) * LDB + bb] = f2bf(a.w);
    }
    #pragma unroll
    for (int j = 0; j < 10; ++j) {
        int q = j * 256 + tid;
        int n = q >> 4, s = q & 15;
        *(short8*)(&Bs2[n * LDB + s * 8]) =
            *(const short8*)(Vt + n * 256 + b0 + s * 8);
    }
    __syncthreads();

    const int wv = tid >> 6, lane = tid & 63;
    const int lrow = lane & 15, quad = lane >> 4;
    f32x4 acc[5][3];
    #pragma unroll
    for (int mt = 0; mt < 5; ++mt)
        #pragma unroll
        for (int sl = 0; sl < 3; ++sl) acc[mt][sl] = (f32x4)(0.0f);

    #pragma unroll
    for (int kb = 0; kb < 4; ++kb) {
        const int ko = kb * 32 + quad * 8;
        short8 af[5], bf[3];
        #pragma unroll
        for (int mt = 0; mt < 5; ++mt)
            af[mt] = *(const short8*)(&As[(mt * 16 + lrow) * LDB + ko]);
        #pragma unroll
        for (int sl = 0; sl < 3; ++sl) {
            int nt = wv + sl * 4;
            if (nt < 10)
                bf[sl] = *(const short8*)(&Bs2[(nt * 16 + lrow) * LDB + ko]);
        }
        #pragma unroll
        for (int mt = 0; mt < 5; ++mt)
            #pragma unroll
            for (int sl = 0; sl < 3; ++sl)
                if (wv + sl * 4 < 10)
                    acc[mt][sl] = __builtin_amdgcn_mfma_f32_16x16x32_bf16(
                        af[mt], bf[sl], acc[mt][sl], 0, 0, 0);
    }
    __syncthreads();

    #pragma unroll
    for (int mt = 0; mt < 5; ++mt) {
        #pragma unroll
        for (int sl = 0; sl < 3; ++sl) {
            int nt = wv + sl * 4;
            if (nt < 10) {
                #pragma unroll
                for (int reg = 0; reg < 4; ++reg) {
                    int m = mt * 16 + quad * 4 + reg;
                    if (m < 72)
                        LG[m * 165 + nt * 16 + lrow] = acc[mt][sl][reg];
                }
            }
        }
    }
    __syncthreads();
    if (tid < 90) {
        int rl = tid / 10, c = tid - rl * 10;
        int r = r0 + rl;
        const float4* wp = (const float4*)(W + (size_t)r * 1280 + c * 128);
        float s = 0.0f;
        #pragma unroll
        for (int o = 0; o < 16; ++o) {
            float4 wa = wp[o * 2], wb = wp[o * 2 + 1];
            const float* g = &LG[(rl * 8) * 165 + c * 16 + o];
            s += wa.x * g[0]       + wa.y * g[165]     + wa.z * g[2 * 165] +
                 wa.w * g[3 * 165] + wb.x * g[4 * 165] + wb.y * g[5 * 165] +
                 wb.z * g[6 * 165] + wb.w * g[7 * 165];
        }
        atomicAdd(&bij[r * 10 + c], s * (1.0f / B_));
    }
}

// ---------------------------------------------------------------------------
extern "C" void kernel_launch(void* const* d_in, const int* in_sizes, int n_in,
                              void* d_out, int out_size, void* d_ws, size_t ws_size,
                              hipStream_t stream) {
    const float* x = (const float*)d_in[0];   // (256, 1152, 8)
    const float* W = (const float*)d_in[1];   // (1152, 10, 16, 8)
    char* ws       = (char*)d_ws;
    _Float16* part = (_Float16*)ws;
    float* bij     = (float*)(ws + BIJ_BOFF);
    short* vt      = (short*)(ws + VT_BOFF);  // Vt[160][256] bf16
    unsigned* bar  = (unsigned*)(ws + BAR_BOFF);
    float* outf    = (float*)d_out;

    // zero the per-ordinal barrier counters (captured as a graph node, so
    // every replay re-arms them)
    hipMemsetAsync((void*)bar, 0, BAR_BYTES, stream);

    void* args[] = {(void*)&x, (void*)&W, (void*)&part,
                    (void*)&bij, (void*)&vt, (void*)&outf, (void*)&bar};
    hipError_t e = hipLaunchCooperativeKernel((const void*)k_caps, dim3(256),
                                              dim3(256), args, 0, stream);
    if (e != hipSuccess) {
        // fallback: verified 8-dispatch path
        for (int it = 0; it < 3; ++it) {
            k_gemm<<<256, 256, 0, stream>>>(x, W, bij, part, it);
            k_reduce<<<256, 256, 0, stream>>>(part, outf, vt, it == 2);
            if (it < 2) k_gtdot<<<256, 256, 0, stream>>>(x, W, vt, bij);
        }
    }
}